// Round 8
// baseline (30.353 us; speedup 1.0000x reference)
//
#include <hip/hip_runtime.h>
#include <stdint.h>

typedef float float4v __attribute__((ext_vector_type(4)));
typedef float float2v __attribute__((ext_vector_type(2)));

#define BLK 256

// robust criterion parse: int32, else f32, else default -1
__device__ __forceinline__ int read_crit(const void* p) {
    const int ci = *(const int*)p;
    if (ci >= -2 && ci <= 3) return ci;
    const float cf = *(const float*)p;
    if (cf == cf && fabsf(cf) <= 4.0f && cf == truncf(cf)) return (int)cf;
    return -1;
}

// Output layout (all float32):
//   [0, 4KN)     overlaps (K*N, 4)
//   [4KN, 6KN)   tensor_index (K*N, 2)  values k, n as float
//   [6KN, 7KN)   valid (K*N)            1.0 / 0.0
//
// Stream-specialized blocks: gridDim.z picks the output stream so every
// wave emits exactly ONE linear write stream (mimics the 6.6 TB/s fill
// kernel). z=0: overlaps (float4/lane). z=1: tensor_index (float4/lane,
// 2 pairs, no loads). z=2: valid (float2/lane, 2 pairs).
// Dispatch is x,y-major then z -> three near-sequential pure phases.
__global__ __launch_bounds__(256) void clocs_kernel(
    const float4v* __restrict__ boxes,   // N x 4 f32
    const float4v* __restrict__ qboxes,  // K x 4 f32
    const float*   __restrict__ s3d,     // N f32
    const float*   __restrict__ s2d,     // K f32
    const float*   __restrict__ dis,     // N f32
    const void*    __restrict__ crit_p,
    float*         __restrict__ out,
    int N, int K)
{
    const int k = blockIdx.y;
    const int z = blockIdx.z;
    const size_t KN = (size_t)K * (size_t)N;

    if (z == 0) {
        // ---- overlaps stream: one pair per thread, float4 store ----
        const int n = blockIdx.x * BLK + threadIdx.x;
        if (n >= N) return;

        const float4v qb = qboxes[k];                 // uniform (s_load)
        const float qarea = (qb.z - qb.x) * (qb.w - qb.y);
        const float sc2   = s2d[k];
        const int   crit  = read_crit(crit_p);

        const float4v b  = boxes[n];
        const float   s3 = s3d[n];
        const float   dl = dis[n];

        const float iw = fminf(b.z, qb.z) - fmaxf(b.x, qb.x);
        const float ih = fminf(b.w, qb.w) - fmaxf(b.y, qb.y);
        const bool  valid = (iw > 0.0f) && (ih > 0.0f);
        const float inter = iw * ih;
        const float barea = (b.z - b.x) * (b.w - b.y);
        float ua;
        if (crit == -1)      ua = barea + qarea - inter;
        else if (crit == 0)  ua = barea;
        else if (crit == 1)  ua = qarea;
        else                 ua = 1.0f;
        const float iou = (ua != 0.0f) ? (inter / ua) : 0.0f;

        float4v ov;
        ov.x = valid ? iou : -10.0f;
        ov.y = s3;
        ov.z = valid ? sc2 : -10.0f;
        ov.w = dl;

        const size_t p = (size_t)k * (size_t)N + (size_t)n;
        *(float4v*)(out + p * 4) = ov;

    } else if (z == 1) {
        // ---- tensor_index stream: 2 pairs per thread, float4 store, no loads ----
        const int n = (blockIdx.x * BLK + threadIdx.x) * 2;
        if (n >= N) return;

        float4v ix;
        ix.x = (float)k; ix.y = (float)n;
        ix.z = (float)k; ix.w = (float)(n + 1);

        const size_t p = (size_t)k * (size_t)N + (size_t)n;
        *(float4v*)(out + KN * 4 + p * 2) = ix;   // 16B aligned (n even)

    } else {
        // ---- valid stream: 2 pairs per thread, float2 store ----
        const int n = (blockIdx.x * BLK + threadIdx.x) * 2;
        if (n >= N) return;

        const float4v qb = qboxes[k];
        const float4v b0 = boxes[n + 0];
        const float4v b1 = boxes[n + 1];

        float2v v;
        {
            const float iw = fminf(b0.z, qb.z) - fmaxf(b0.x, qb.x);
            const float ih = fminf(b0.w, qb.w) - fmaxf(b0.y, qb.y);
            v.x = (iw > 0.0f && ih > 0.0f) ? 1.0f : 0.0f;
        }
        {
            const float iw = fminf(b1.z, qb.z) - fmaxf(b1.x, qb.x);
            const float ih = fminf(b1.w, qb.w) - fmaxf(b1.y, qb.y);
            v.y = (iw > 0.0f && ih > 0.0f) ? 1.0f : 0.0f;
        }

        const size_t p = (size_t)k * (size_t)N + (size_t)n;
        *(float2v*)(out + KN * 6 + p) = v;        // 8B aligned (p even)
    }
}

extern "C" void kernel_launch(void* const* d_in, const int* in_sizes, int n_in,
                              void* d_out, int out_size, void* d_ws, size_t ws_size,
                              hipStream_t stream) {
    const float4v* boxes  = (const float4v*)d_in[0];
    const float4v* qboxes = (const float4v*)d_in[1];
    const float*   s3d    = (const float*)d_in[2];
    const float*   s2d    = (const float*)d_in[3];
    const float*   dis    = (const float*)d_in[4];

    const int N = in_sizes[0] / 4;   // 10000
    const int K = in_sizes[1] / 4;   // 500
    // x sized for z=0 (1 pair/thread): ceil(N/256)=40. z=1/z=2 blocks with
    // x >= ceil(N/2/256)=20 exit immediately (cheap).
    dim3 grid((N + BLK - 1) / BLK, K, 3);

    clocs_kernel<<<grid, dim3(BLK, 1, 1), 0, stream>>>(
        boxes, qboxes, s3d, s2d, dis, d_in[5],
        (float*)d_out, N, K);
}

// Round 9
// 28.071 us; speedup vs baseline: 1.0813x; 1.0813x over previous
//
#include <hip/hip_runtime.h>
#include <stdint.h>

typedef float float4v __attribute__((ext_vector_type(4)));
typedef float float2v __attribute__((ext_vector_type(2)));

#define BLK 256
#define NBLOCKS 2048

// robust criterion parse: int32, else f32, else default -1
__device__ __forceinline__ int read_crit(const void* p) {
    const int ci = *(const int*)p;
    if (ci >= -2 && ci <= 3) return ci;
    const float cf = *(const float*)p;
    if (cf == cf && fabsf(cf) <= 4.0f && cf == truncf(cf)) return (int)cf;
    return -1;
}

// Output layout (all float32):
//   [0, 4KN)     overlaps (K*N, 4)
//   [4KN, 6KN)   tensor_index (K*N, 2)  values k, n as float
//   [6KN, 7KN)   valid (K*N)            1.0 / 0.0
//
// R5 body (1 pair/thread, 3 lane-contiguous stores — fastest so far) run as
// a persistent grid-stride kernel: 2048 blocks sweep 20000 chunks in
// chunk-linear order, so the instantaneous global write window stays
// contiguous (like the 6.5 TB/s fill kernel) while block-dispatch count
// drops 10x.
__global__ __launch_bounds__(256) void clocs_kernel(
    const float4v* __restrict__ boxes,   // N x 4 f32
    const float4v* __restrict__ qboxes,  // K x 4 f32
    const float*   __restrict__ s3d,     // N f32
    const float*   __restrict__ s2d,     // K f32
    const float*   __restrict__ dis,     // N f32
    const void*    __restrict__ crit_p,
    float*         __restrict__ out,
    int N, int K)
{
    const int cpk     = (N + BLK - 1) / BLK;   // chunks per k-row (40)
    const int nchunks = K * cpk;               // 20000
    const size_t KN   = (size_t)K * (size_t)N;
    const int crit    = read_crit(crit_p);
    const int tid     = threadIdx.x;

    for (int c = blockIdx.x; c < nchunks; c += NBLOCKS) {
        const int k  = c / cpk;                // uniform across block
        const int n  = (c - k * cpk) * BLK + tid;
        if (n >= N) continue;

        const float4v qb = qboxes[k];          // wave-uniform broadcast
        const float qarea = (qb.z - qb.x) * (qb.w - qb.y);
        const float sc2   = s2d[k];

        const float4v b  = boxes[n];
        const float   s3 = s3d[n];
        const float   dl = dis[n];

        const float iw = fminf(b.z, qb.z) - fmaxf(b.x, qb.x);
        const float ih = fminf(b.w, qb.w) - fmaxf(b.y, qb.y);
        const bool  valid = (iw > 0.0f) && (ih > 0.0f);
        const float inter = iw * ih;
        const float barea = (b.z - b.x) * (b.w - b.y);
        float ua;
        if (crit == -1)      ua = barea + qarea - inter;
        else if (crit == 0)  ua = barea;
        else if (crit == 1)  ua = qarea;
        else                 ua = 1.0f;
        const float iou = (ua != 0.0f) ? (inter / ua) : 0.0f;

        float4v ov;
        ov.x = valid ? iou : -10.0f;
        ov.y = s3;
        ov.z = valid ? sc2 : -10.0f;
        ov.w = dl;

        float2v ix;
        ix.x = (float)k;
        ix.y = (float)n;

        const size_t p = (size_t)k * (size_t)N + (size_t)n;

        *(float4v*)(out + p * 4)          = ov;
        *(float2v*)(out + KN * 4 + p * 2) = ix;
        *(out + KN * 6 + p)               = valid ? 1.0f : 0.0f;
    }
}

extern "C" void kernel_launch(void* const* d_in, const int* in_sizes, int n_in,
                              void* d_out, int out_size, void* d_ws, size_t ws_size,
                              hipStream_t stream) {
    const float4v* boxes  = (const float4v*)d_in[0];
    const float4v* qboxes = (const float4v*)d_in[1];
    const float*   s3d    = (const float*)d_in[2];
    const float*   s2d    = (const float*)d_in[3];
    const float*   dis    = (const float*)d_in[4];

    const int N = in_sizes[0] / 4;   // 10000
    const int K = in_sizes[1] / 4;   // 500

    clocs_kernel<<<NBLOCKS, BLK, 0, stream>>>(
        boxes, qboxes, s3d, s2d, dis, d_in[5],
        (float*)d_out, N, K);
}

// Round 10
// 27.206 us; speedup vs baseline: 1.1157x; 1.0318x over previous
//
#include <hip/hip_runtime.h>
#include <stdint.h>

typedef float float4v __attribute__((ext_vector_type(4)));
typedef float float2v __attribute__((ext_vector_type(2)));

// robust criterion parse: int32, else f32, else default -1
__device__ __forceinline__ int read_crit(const void* p) {
    const int ci = *(const int*)p;
    if (ci >= -2 && ci <= 3) return ci;
    const float cf = *(const float*)p;
    if (cf == cf && fabsf(cf) <= 4.0f && cf == truncf(cf)) return (int)cf;
    return -1;
}

// Output layout (all float32):
//   [0, 4KN)     overlaps (K*N, 4)
//   [4KN, 6KN)   tensor_index (K*N, 2)  values k, n as float
//   [6KN, 7KN)   valid (K*N)            1.0 / 0.0
//
// FINAL (R5 structure, empirically fastest at 27.0 µs):
//   grid.x tiles N (one thread per box n), grid.y = k. One pair per thread;
//   all three stores lane-contiguous (float4/float2/float per lane).
// Measured ledger: NT stores −18% (R6), k-tiling neutral (R7),
// stream-specialized blocks −12% (R8), persistent grid-stride −4% (R9).
// Floor = 140 MB @ ~6.5 TB/s (fill-kernel ceiling) + ~5 µs fixed overhead.
__global__ __launch_bounds__(256) void clocs_kernel(
    const float4v* __restrict__ boxes,   // N x 4 f32
    const float4v* __restrict__ qboxes,  // K x 4 f32
    const float*   __restrict__ s3d,     // N f32
    const float*   __restrict__ s2d,     // K f32
    const float*   __restrict__ dis,     // N f32
    const void*    __restrict__ crit_p,
    float*         __restrict__ out,
    int N, int K)
{
    const int n = blockIdx.x * blockDim.x + threadIdx.x;
    if (n >= N) return;
    const int k = blockIdx.y;

    // wave-uniform query data (broadcast loads)
    const float4v qb = qboxes[k];
    const float qx1 = qb.x, qy1 = qb.y, qx2 = qb.z, qy2 = qb.w;
    const float qarea = (qx2 - qx1) * (qy2 - qy1);
    const float sc2   = s2d[k];
    const int   crit  = read_crit(crit_p);

    // lane-contiguous loads
    const float4v b  = boxes[n];
    const float   s3 = s3d[n];
    const float   dl = dis[n];

    const float iw = fminf(b.z, qx2) - fmaxf(b.x, qx1);
    const float ih = fminf(b.w, qy2) - fmaxf(b.y, qy1);
    const bool  valid = (iw > 0.0f) && (ih > 0.0f);
    const float inter = iw * ih;
    const float barea = (b.z - b.x) * (b.w - b.y);
    float ua;
    if (crit == -1)      ua = barea + qarea - inter;
    else if (crit == 0)  ua = barea;
    else if (crit == 1)  ua = qarea;
    else                 ua = 1.0f;
    const float iou = (ua != 0.0f) ? (inter / ua) : 0.0f;

    float4v ov;
    ov.x = valid ? iou : -10.0f;
    ov.y = s3;
    ov.z = valid ? sc2 : -10.0f;
    ov.w = dl;

    float2v ix;
    ix.x = (float)k;
    ix.y = (float)n;

    const size_t p  = (size_t)k * (size_t)N + (size_t)n;
    const size_t KN = (size_t)K * (size_t)N;

    *(float4v*)(out + p * 4)            = ov;   // overlaps row
    *(float2v*)(out + KN * 4 + p * 2)   = ix;   // tensor_index row
    *(out + KN * 6 + p)                 = valid ? 1.0f : 0.0f;
}

extern "C" void kernel_launch(void* const* d_in, const int* in_sizes, int n_in,
                              void* d_out, int out_size, void* d_ws, size_t ws_size,
                              hipStream_t stream) {
    const float4v* boxes  = (const float4v*)d_in[0];
    const float4v* qboxes = (const float4v*)d_in[1];
    const float*   s3d    = (const float*)d_in[2];
    const float*   s2d    = (const float*)d_in[3];
    const float*   dis    = (const float*)d_in[4];

    const int N = in_sizes[0] / 4;   // 10000
    const int K = in_sizes[1] / 4;   // 500
    const int block = 256;
    dim3 grid((N + block - 1) / block, K, 1);

    clocs_kernel<<<grid, dim3(block, 1, 1), 0, stream>>>(
        boxes, qboxes, s3d, s2d, dis, d_in[5],
        (float*)d_out, N, K);
}